// Round 13
// baseline (604.504 us; speedup 1.0000x reference)
//
#include <hip/hip_runtime.h>

#define NROWS 65536
#define KC    1024
#define DD    256
#define ND    (NROWS*DD)      /* 16777216 */
#define KD    (KC*DD)         /* 262144 */
#define BROWS 32              /* rows per main block */
#define CAP   24              /* candidate list capacity per row */
#define MARGIN 3.0f           /* >=2E for bf16-screen vs exact-replica (~14 sigma) */

/* output offsets (floats), concatenated in reference return order */
#define O_ZQ   0
#define O_DIST ND
#define O_IDX  (ND+1)
#define O_EMB  (ND+1+NROWS)
#define O_MT   (O_EMB+KD)
#define O_NT   (O_MT+KD)

/* ws float offsets */
#define WS_WSQ   0
#define WS_WPK   KC                    /* 131072 floats = 512KB bf16 W frags */
#define WS_ROWC  (KC+131072)           /* NROWS ints */
#define WS_BUCK  (WS_ROWC+NROWS)       /* NROWS ints */
#define WS_OFFS  (WS_BUCK+NROWS)       /* 1028 ints (1025 used) */
#define WS_POS   (WS_OFFS+1028)        /* KC ints */
#define WS_CNT   (WS_POS+KC)           /* KC ints */
#define WS_DIST  (WS_CNT+KC)           /* 1 float + 3 pad */
#define WS_ST    (WS_DIST+4)           /* KD floats, 16B aligned */

typedef __attribute__((ext_vector_type(8))) short bf16x8;
typedef __attribute__((ext_vector_type(4))) float f32x4;

/* ===== exact-replica arithmetic contract (validated rounds 5-11) =====
   ref dist d2[r][c] = fadd( fsub( zsq[r], fmul(2, dot) ), wsq[c] )
   dot  = sequential ascending-k, SEPARATE mul+add roundings, single acc
   zsq/wsq = strict sequential sum of squares (mul+add, ascending)
   argmin  = first occurrence of min.
   Screen = bf16 MFMA (row-constant zsq dropped, absorbed in MARGIN);
   every code within MARGIN of the row's global screen min is rescored
   with the exact chain.  Phase-3 code is round-11's verbatim (the round-12
   restructure failed for an unidentified reason and is reverted). */

static __device__ __forceinline__ void minmerge(float& bv, int& bi, float ov, int oi){
  if (ov < bv || (ov == bv && oi < bi)) { bv = ov; bi = oi; }
}

static __device__ __forceinline__ unsigned short f2bf(float f){
  unsigned u = __float_as_uint(f);
  unsigned r = (u + 0x7FFFu + ((u>>16)&1u)) >> 16;   /* RNE */
  return (unsigned short)r;
}
static __device__ __forceinline__ bf16x8 cvt8(float4 a, float4 b){
  bf16x8 v;
  v[0]=(short)f2bf(a.x); v[1]=(short)f2bf(a.y); v[2]=(short)f2bf(a.z); v[3]=(short)f2bf(a.w);
  v[4]=(short)f2bf(b.x); v[5]=(short)f2bf(b.y); v[6]=(short)f2bf(b.z); v[7]=(short)f2bf(b.w);
  return v;
}

/* merged prologue: one wave per code. Lanes 0-31 pack bf16 B-fragments,
   lane 32 runs the exact wsq chain (scalar, round-11 verbatim). */
__global__ __launch_bounds__(256,1) void vq_prep_kernel(const float* __restrict__ W,
                                                        float* __restrict__ wsq,
                                                        bf16x8* __restrict__ wpk){
  const int wv = threadIdx.x>>6, lane = threadIdx.x&63;
  const int k = blockIdx.x*4 + wv;
  const float* wr = W + (size_t)k*DD;
  if (lane < 32){
    float4 x = *(const float4*)(wr + lane*8);
    float4 y = *(const float4*)(wr + lane*8 + 4);
    wpk[((k>>4)*8 + (lane>>2))*64 + (k&15) + 16*(lane&3)] = cvt8(x,y);
  } else if (lane == 32){
    float s = __fmul_rn(wr[0], wr[0]);
    for (int i=1;i<256;i++) s = __fadd_rn(s, __fmul_rn(wr[i], wr[i]));
    wsq[k] = s;
  }
}

/* Main: 256 thr = 4 waves (4 col-groups), 32 rows x 1024 codes per block,
   2048 blocks, 5 blocks/CU (LDS ~27 KB). Decision path == round 11. */
__global__ __launch_bounds__(256,5) void vq_main_kernel(
    const float* __restrict__ ze, const float* __restrict__ W,
    const bf16x8* __restrict__ wpk, const float* __restrict__ wsq,
    float* __restrict__ out, int* __restrict__ rowcode, int* __restrict__ cnt,
    float* __restrict__ dist_acc)
{
  __shared__ bf16x8 apkS[1024];        /* 16 KB: A fragments, linear */
  __shared__ float  wsqS[KC];          /* 4 KB */
  __shared__ float  gminW[8][BROWS];   /* 1 KB: per-(pass,cg) row mins */
  __shared__ int    cntS[BROWS];
  __shared__ float  listV[BROWS][CAP]; /* 3 KB */
  __shared__ int    listI[BROWS][CAP]; /* 3 KB */
  __shared__ int    riS[BROWS];

  const int tid = threadIdx.x;
  const int blk = blockIdx.x;
  const float* zb = ze + (size_t)blk*BROWS*DD;

  /* ---- phase 1: convert z tile to A fragments + init ---- */
  #pragma unroll
  for (int it=0; it<4; ++it){
    const int g  = it*256 + tid;       /* 0..1023 */
    const int r  = g >> 5;             /* row 0..31 */
    const int kb = g & 31;             /* k-block of 8 */
    float4 a = *(const float4*)&zb[(size_t)r*DD + kb*8];
    float4 b = *(const float4*)&zb[(size_t)r*DD + kb*8 + 4];
    apkS[((r>>4)*8 + (kb>>2))*64 + (r&15) + 16*(kb&3)] = cvt8(a,b);
  }
  #pragma unroll
  for (int i=0;i<4;i++) wsqS[i*256 + tid] = wsq[i*256 + tid];
  if (tid < BROWS) cntS[tid] = 0;
  __syncthreads();

  /* ---- phase 2: MFMA screen + per-group min + candidate collection ---- */
  const int lane = tid & 63;
  const int cg   = tid >> 6;       /* 0..3 : 256-col group */

  #pragma unroll
  for (int p=0; p<2; ++p){
    f32x4 acc[2][8];
    #pragma unroll
    for (int mt=0; mt<2; ++mt)
      #pragma unroll
      for (int nt=0; nt<8; ++nt)
        acc[mt][nt] = (f32x4){0.f,0.f,0.f,0.f};

    #pragma unroll
    for (int s=0; s<8; ++s){
      bf16x8 af[2], bf[8];
      #pragma unroll
      for (int mt=0; mt<2; ++mt)
        af[mt] = apkS[(mt*8 + s)*64 + lane];
      #pragma unroll
      for (int nt=0; nt<8; ++nt)
        bf[nt] = wpk[(size_t)(((cg*16 + p*8 + nt)*8 + s)*64 + lane)];
      #pragma unroll
      for (int mt=0; mt<2; ++mt)
        #pragma unroll
        for (int nt=0; nt<8; ++nt)
          acc[mt][nt] = __builtin_amdgcn_mfma_f32_16x16x32_bf16(af[mt], bf[nt], acc[mt][nt], 0,0,0);
    }

    /* screen value = wsq - 2*dot (row-constant zsq dropped) */
    #pragma unroll
    for (int mt=0; mt<2; ++mt){
      #pragma unroll
      for (int r=0; r<4; ++r){
        const int row = mt*16 + (lane>>4)*4 + r;
        float dv[8]; float mn = 3.4e38f;
        #pragma unroll
        for (int nt=0; nt<8; ++nt){
          const int col = (cg*16 + p*8 + nt)*16 + (lane&15);
          dv[nt] = __fsub_rn(wsqS[col], __fmul_rn(2.0f, acc[mt][nt][r]));
          mn = fminf(mn, dv[nt]);
        }
        #pragma unroll
        for (int m=1; m<16; m<<=1) mn = fminf(mn, __shfl_xor(mn, m));
        if ((lane & 15) == 0) gminW[p*4+cg][row] = mn;
        const float thr = mn + MARGIN;
        #pragma unroll
        for (int nt=0; nt<8; ++nt){
          if (dv[nt] <= thr){
            int slot = atomicAdd(&cntS[row], 1);
            if (slot < CAP){
              listV[row][slot] = dv[nt];
              listI[row][slot] = (cg*16 + p*8 + nt)*16 + (lane&15);
            }
          }
        }
      }
    }
  }
  __syncthreads();

  /* ---- phase 3: global-min filter + exact-replica rescore (1 thr/row),
          round-11 verbatim ---- */
  if (tid < BROWS){
    const int rr = tid;
    const float* zr = zb + (size_t)rr*DD;
    /* exact zsq chain */
    float zs = __fmul_rn(zr[0], zr[0]);
    for (int i=1;i<256;i++) zs = __fadd_rn(zs, __fmul_rn(zr[i], zr[i]));
    float g = gminW[0][rr];
    #pragma unroll
    for (int q=1;q<8;q++) g = fminf(g, gminW[q][rr]);
    const float fthr = g + MARGIN;
    int c = cntS[rr]; if (c > CAP) c = CAP;
    float bv = 3.4e38f; int bi = 0x7fffffff;
    for (int i=0;i<c;i++){
      if (listV[rr][i] <= fthr){
        const int idx = listI[rr][i];
        const float* wr = W + (size_t)idx*DD;
        float ss = 0.f;
        for (int k2=0;k2<256;k2++) ss = __fadd_rn(ss, __fmul_rn(zr[k2], wr[k2]));
        const float v = __fadd_rn(__fsub_rn(zs, __fmul_rn(2.0f, ss)), wsqS[idx]);
        minmerge(bv, bi, v, idx);
      }
    }
    riS[rr] = bi;
    const int grow = blk*BROWS + rr;
    rowcode[grow] = bi;
    out[O_IDX + grow] = (float)bi;
    atomicAdd(&cnt[bi], 1);
  }
  __syncthreads();

  /* ---- phase 4: epilogue (zq_st, dist) ---- */
  float distp = 0.f;
  const int GRp = tid >> 5;   /* 0..7, 4 rows each */
  const int TX  = tid & 31;
  #pragma unroll
  for (int e=0; e<4; ++e){
    const int r    = GRp*4 + e;
    const int grow = blk*BROWS + r;
    const int gi   = riS[r];
    const float* wrow = W + (size_t)gi*DD;
    const float* zrow = zb + (size_t)r*DD;
    #pragma unroll
    for (int j=0;j<2;j++){
      const int d = 128*j + 4*TX;
      float4 w4 = *(const float4*)(wrow + d);
      float4 z4 = *(const float4*)(zrow + d);
      float4 o;
      o.x = z4.x + (w4.x - z4.x);
      o.y = z4.y + (w4.y - z4.y);
      o.z = z4.z + (w4.z - z4.z);
      o.w = z4.w + (w4.w - z4.w);
      *(float4*)&out[(size_t)grow*DD + d] = o;
      float dx;
      dx = w4.x - z4.x; distp += dx*dx;
      dx = w4.y - z4.y; distp += dx*dx;
      dx = w4.z - z4.z; distp += dx*dx;
      dx = w4.w - z4.w; distp += dx*dx;
    }
  }
  #pragma unroll
  for (int m=1; m<64; m<<=1) distp += __shfl_xor(distp, m);
  if ((tid & 63) == 0) atomicAdd(dist_acc, distp);
}

/* exclusive prefix sum over 1024 counts -> offs (with sentinel), pos */
__global__ __launch_bounds__(1024,1) void vq_prefix_kernel(
    const int* __restrict__ cnt, int* __restrict__ offs, int* __restrict__ pos)
{
  __shared__ int s[1024];
  const int tid = threadIdx.x;
  const int c = cnt[tid];
  s[tid] = c;
  __syncthreads();
  #pragma unroll
  for (int off=1; off<1024; off<<=1){
    int v = s[tid];
    int a = (tid >= off) ? s[tid-off] : 0;
    __syncthreads();
    s[tid] = v + a;
    __syncthreads();
  }
  const int ex = s[tid] - c;
  offs[tid] = ex;
  pos[tid]  = ex;
  if (tid == 1023) offs[1024] = NROWS;
}

/* bucket row ids by code */
__global__ __launch_bounds__(256,1) void vq_scatter_kernel(
    const int* __restrict__ rowcode, int* __restrict__ pos, int* __restrict__ bucket)
{
  const int r = blockIdx.x*256 + threadIdx.x;
  const int k = rowcode[r];
  const int slot = atomicAdd(&pos[k], 1);
  bucket[slot] = r;
}

/* balanced chunk-parallel segmented sum over the code-sorted bucket */
__global__ __launch_bounds__(256,4) void vq_chunksum_kernel(
    const float* __restrict__ ze, const int* __restrict__ bucket,
    const int* __restrict__ offs, float* __restrict__ st)
{
  __shared__ int offsS[1025];
  const int tid = threadIdx.x;
  for (int i=tid; i<1025; i+=256) offsS[i] = offs[i];
  __syncthreads();

  const int wv = tid >> 6, lane = tid & 63;
  const int j0 = (blockIdx.x*4 + wv)*32;

  int r, k;
  {
    const int j = j0 + (lane & 31);
    r = bucket[j];
    int lo = 0, hi = 1024;
    #pragma unroll
    for (int it=0; it<10; ++it){
      int mid = (lo + hi) >> 1;
      if (offsS[mid] <= j) lo = mid; else hi = mid;
    }
    k = lo;
  }

  float4 acc = {0.f,0.f,0.f,0.f};
  int kprev = __shfl(k, 0);
  #pragma unroll
  for (int g=0; g<4; ++g){
    float4 v[8]; int rk[8];
    #pragma unroll
    for (int i=0;i<8;i++){
      const int ri = __shfl(r, g*8+i);
      rk[i] = __shfl(k, g*8+i);
      v[i] = *(const float4*)&ze[(size_t)ri*DD + lane*4];
    }
    #pragma unroll
    for (int i=0;i<8;i++){
      if (rk[i] != kprev){
        atomicAdd(&st[(size_t)kprev*DD + lane*4 + 0], acc.x);
        atomicAdd(&st[(size_t)kprev*DD + lane*4 + 1], acc.y);
        atomicAdd(&st[(size_t)kprev*DD + lane*4 + 2], acc.z);
        atomicAdd(&st[(size_t)kprev*DD + lane*4 + 3], acc.w);
        acc = (float4){0.f,0.f,0.f,0.f};
        kprev = rk[i];
      }
      acc.x += v[i].x; acc.y += v[i].y; acc.z += v[i].z; acc.w += v[i].w;
    }
  }
  atomicAdd(&st[(size_t)kprev*DD + lane*4 + 0], acc.x);
  atomicAdd(&st[(size_t)kprev*DD + lane*4 + 1], acc.y);
  atomicAdd(&st[(size_t)kprev*DD + lane*4 + 2], acc.z);
  atomicAdd(&st[(size_t)kprev*DD + lane*4 + 3], acc.w);
}

/* EMA tail: mt_new, embedW_new, Nt_new, dist */
__global__ __launch_bounds__(256,1) void vq_tail_kernel(
    const float* __restrict__ mt, const float* __restrict__ Nt,
    const float* __restrict__ st, const int* __restrict__ cnt,
    const float* __restrict__ dist_acc, float* __restrict__ out)
{
  const float G   = 0.99f;
  const float OMG = (float)(1.0 - 0.99);
  const int i = blockIdx.x*256 + threadIdx.x;   /* 0..KD-1 */
  const int k = i >> 8;
  const float ntn = __fadd_rn(__fmul_rn(G, Nt[k]), __fmul_rn(OMG, (float)cnt[k]));
  const float mtn = __fadd_rn(__fmul_rn(G, mt[i]), __fmul_rn(OMG, st[i]));
  out[O_MT  + i] = mtn;
  out[O_EMB + i] = mtn / ntn;
  if ((i & 255) == 0) out[O_NT + k] = ntn;
  if (i == 0) out[O_DIST] = dist_acc[0] * (1.0f/16777216.0f);
}

extern "C" void kernel_launch(void* const* d_in, const int* in_sizes, int n_in,
                              void* d_out, int out_size, void* d_ws, size_t ws_size,
                              hipStream_t stream){
  const float* ze = (const float*)d_in[0];
  const float* W  = (const float*)d_in[1];
  const float* mt = (const float*)d_in[2];
  const float* Nt = (const float*)d_in[3];
  float* out  = (float*)d_out;
  float* ws   = (float*)d_ws;
  float*  wsq  = ws + WS_WSQ;
  bf16x8* wpk  = (bf16x8*)(ws + WS_WPK);
  int*    rowc = (int*)(ws + WS_ROWC);
  int*    buck = (int*)(ws + WS_BUCK);
  int*    offs = (int*)(ws + WS_OFFS);
  int*    pos  = (int*)(ws + WS_POS);
  int*    cnt  = (int*)(ws + WS_CNT);
  float*  dist = ws + WS_DIST;
  float*  st   = ws + WS_ST;

  /* zero cnt + dist(+pad) + st in one shot (contiguous) */
  hipMemsetAsync((void*)(ws + WS_CNT), 0, (size_t)(KC + 4 + KD)*sizeof(float), stream);
  vq_prep_kernel    <<<KC/4,        256, 0, stream>>>(W, wsq, wpk);
  vq_main_kernel    <<<NROWS/BROWS, 256, 0, stream>>>(ze, W, wpk, wsq, out, rowc, cnt, dist);
  vq_prefix_kernel  <<<1,          1024, 0, stream>>>(cnt, offs, pos);
  vq_scatter_kernel <<<NROWS/256,   256, 0, stream>>>(rowc, pos, buck);
  vq_chunksum_kernel<<<NROWS/128,   256, 0, stream>>>(ze, buck, offs, st);
  vq_tail_kernel    <<<KD/256,      256, 0, stream>>>(mt, Nt, st, cnt, dist, out);
}

// Round 14
// 439.926 us; speedup vs baseline: 1.3741x; 1.3741x over previous
//
#include <hip/hip_runtime.h>

#define NROWS 65536
#define KC    1024
#define DD    256
#define ND    (NROWS*DD)      /* 16777216 */
#define KD    (KC*DD)         /* 262144 */
#define BROWS 64              /* rows per main block */
#define CAP   24              /* candidate list capacity per row */
#define MARGIN 3.0f           /* >=2E for bf16-screen vs exact-replica (~14 sigma) */

/* output offsets (floats), concatenated in reference return order */
#define O_ZQ   0
#define O_DIST ND
#define O_IDX  (ND+1)
#define O_EMB  (ND+1+NROWS)
#define O_MT   (O_EMB+KD)
#define O_NT   (O_MT+KD)

/* ws float offsets */
#define WS_WSQ   0
#define WS_WPK   KC                    /* 131072 floats = 512KB bf16 W frags */
#define WS_ROWC  (KC+131072)           /* NROWS ints */
#define WS_BUCK  (WS_ROWC+NROWS)       /* NROWS ints */
#define WS_OFFS  (WS_BUCK+NROWS)       /* 1028 ints (1025 used) */
#define WS_POS   (WS_OFFS+1028)        /* KC ints */
#define WS_CNT   (WS_POS+KC)           /* KC ints */
#define WS_DIST  (WS_CNT+KC)           /* 1 float + 3 pad */
#define WS_ST    (WS_DIST+4)           /* KD floats, 16B aligned */

typedef __attribute__((ext_vector_type(8))) short bf16x8;
typedef __attribute__((ext_vector_type(4))) float f32x4;

/* ===== exact-replica arithmetic contract (validated rounds 5-11,13) =====
   ref dist d2[r][c] = fadd( fsub( zsq[r], fmul(2, dot) ), wsq[c] )
   dot  = sequential ascending-k, SEPARATE mul+add roundings, single acc
   zsq/wsq = strict sequential sum of squares (mul+add, ascending)
   argmin  = first occurrence of min.
   Screen = bf16 MFMA (row-constant zsq dropped, absorbed in MARGIN);
   every code within MARGIN of the row's global screen min is rescored
   with the exact chain.  Phase-3 body is round-11 verbatim; the ONLY
   change vs round 11 is the row->thread mapping (rr = tid>>3, 8 active
   lanes/wave) so all 8 waves run chains with 8x less load divergence. */

static __device__ __forceinline__ void minmerge(float& bv, int& bi, float ov, int oi){
  if (ov < bv || (ov == bv && oi < bi)) { bv = ov; bi = oi; }
}

static __device__ __forceinline__ unsigned short f2bf(float f){
  unsigned u = __float_as_uint(f);
  unsigned r = (u + 0x7FFFu + ((u>>16)&1u)) >> 16;   /* RNE */
  return (unsigned short)r;
}
static __device__ __forceinline__ bf16x8 cvt8(float4 a, float4 b){
  bf16x8 v;
  v[0]=(short)f2bf(a.x); v[1]=(short)f2bf(a.y); v[2]=(short)f2bf(a.z); v[3]=(short)f2bf(a.w);
  v[4]=(short)f2bf(b.x); v[5]=(short)f2bf(b.y); v[6]=(short)f2bf(b.z); v[7]=(short)f2bf(b.w);
  return v;
}

/* merged prologue: one wave per code. Lanes 0-31 pack bf16 B-fragments,
   lane 32 runs the exact wsq chain (scalar, round-11 verbatim). */
__global__ __launch_bounds__(256,1) void vq_prep_kernel(const float* __restrict__ W,
                                                        float* __restrict__ wsq,
                                                        bf16x8* __restrict__ wpk){
  const int wv = threadIdx.x>>6, lane = threadIdx.x&63;
  const int k = blockIdx.x*4 + wv;
  const float* wr = W + (size_t)k*DD;
  if (lane < 32){
    float4 x = *(const float4*)(wr + lane*8);
    float4 y = *(const float4*)(wr + lane*8 + 4);
    wpk[((k>>4)*8 + (lane>>2))*64 + (k&15) + 16*(lane&3)] = cvt8(x,y);
  } else if (lane == 32){
    float s = __fmul_rn(wr[0], wr[0]);
    for (int i=1;i<256;i++) s = __fadd_rn(s, __fmul_rn(wr[i], wr[i]));
    wsq[k] = s;
  }
}

/* Main: 512 thr = 8 waves (2 row-groups x 4 col-groups), 64 rows x 1024
   codes per block, 1024 blocks, 2 blocks/CU. Decision path == round 11. */
__global__ __launch_bounds__(512,2) void vq_main_kernel(
    const float* __restrict__ ze, const float* __restrict__ W,
    const bf16x8* __restrict__ wpk, const float* __restrict__ wsq,
    float* __restrict__ out, int* __restrict__ rowcode, int* __restrict__ cnt,
    float* __restrict__ dist_acc)
{
  __shared__ bf16x8 apkS[2048];        /* 32 KB: A fragments, linear */
  __shared__ float  wsqS[KC];          /* 4 KB */
  __shared__ float  gminW[8][BROWS];   /* 2 KB: per-(pass,cg) row mins */
  __shared__ int    cntS[BROWS];
  __shared__ float  listV[BROWS][CAP]; /* 6 KB */
  __shared__ int    listI[BROWS][CAP]; /* 6 KB */
  __shared__ int    riS[BROWS];

  const int tid = threadIdx.x;
  const int blk = blockIdx.x;
  const float* zb = ze + (size_t)blk*BROWS*DD;

  /* ---- phase 1: convert z tile to A fragments + init ---- */
  #pragma unroll
  for (int it=0; it<4; ++it){
    const int g  = it*512 + tid;
    const int r  = g >> 5;
    const int kb = g & 31;
    float4 a = *(const float4*)&zb[(size_t)r*DD + kb*8];
    float4 b = *(const float4*)&zb[(size_t)r*DD + kb*8 + 4];
    apkS[((r>>4)*8 + (kb>>2))*64 + (r&15) + 16*(kb&3)] = cvt8(a,b);
  }
  wsqS[tid]     = wsq[tid];
  wsqS[tid+512] = wsq[tid+512];
  if (tid < BROWS) cntS[tid] = 0;
  __syncthreads();

  /* ---- phase 2: MFMA screen + per-group min + candidate collection ---- */
  const int lane = tid & 63;
  const int wv   = tid >> 6;
  const int rg   = wv >> 2;
  const int cg   = wv & 3;

  #pragma unroll
  for (int p=0; p<2; ++p){
    f32x4 acc[2][8];
    #pragma unroll
    for (int mt=0; mt<2; ++mt)
      #pragma unroll
      for (int nt=0; nt<8; ++nt)
        acc[mt][nt] = (f32x4){0.f,0.f,0.f,0.f};

    #pragma unroll
    for (int s=0; s<8; ++s){
      bf16x8 af[2], bf[8];
      #pragma unroll
      for (int mt=0; mt<2; ++mt)
        af[mt] = apkS[((rg*2+mt)*8 + s)*64 + lane];
      #pragma unroll
      for (int nt=0; nt<8; ++nt)
        bf[nt] = wpk[(size_t)(((cg*16 + p*8 + nt)*8 + s)*64 + lane)];
      #pragma unroll
      for (int mt=0; mt<2; ++mt)
        #pragma unroll
        for (int nt=0; nt<8; ++nt)
          acc[mt][nt] = __builtin_amdgcn_mfma_f32_16x16x32_bf16(af[mt], bf[nt], acc[mt][nt], 0,0,0);
    }

    /* screen value = wsq - 2*dot (row-constant zsq dropped) */
    #pragma unroll
    for (int mt=0; mt<2; ++mt){
      #pragma unroll
      for (int r=0; r<4; ++r){
        const int row = rg*32 + mt*16 + (lane>>4)*4 + r;
        float dv[8]; float mn = 3.4e38f;
        #pragma unroll
        for (int nt=0; nt<8; ++nt){
          const int col = (cg*16 + p*8 + nt)*16 + (lane&15);
          dv[nt] = __fsub_rn(wsqS[col], __fmul_rn(2.0f, acc[mt][nt][r]));
          mn = fminf(mn, dv[nt]);
        }
        #pragma unroll
        for (int m=1; m<16; m<<=1) mn = fminf(mn, __shfl_xor(mn, m));
        if ((lane & 15) == 0) gminW[p*4+cg][row] = mn;
        const float thr = mn + MARGIN;
        #pragma unroll
        for (int nt=0; nt<8; ++nt){
          if (dv[nt] <= thr){
            int slot = atomicAdd(&cntS[row], 1);
            if (slot < CAP){
              listV[row][slot] = dv[nt];
              listI[row][slot] = (cg*16 + p*8 + nt)*16 + (lane&15);
            }
          }
        }
      }
    }
  }
  __syncthreads();

  /* ---- phase 3: global-min filter + exact-replica rescore.
          Body is round-11 VERBATIM; only the row->thread mapping changed:
          row rr -> thread rr*8, so 8 lanes/wave active on all 8 waves
          (8x less load divergence, 8x wave parallelism). ---- */
  if ((tid & 7) == 0){
    const int rr = tid >> 3;           /* 0..63 */
    const float* zr = zb + (size_t)rr*DD;
    /* exact zsq chain */
    float zs = __fmul_rn(zr[0], zr[0]);
    for (int i=1;i<256;i++) zs = __fadd_rn(zs, __fmul_rn(zr[i], zr[i]));
    float g = gminW[0][rr];
    #pragma unroll
    for (int q=1;q<8;q++) g = fminf(g, gminW[q][rr]);
    const float fthr = g + MARGIN;
    int c = cntS[rr]; if (c > CAP) c = CAP;
    float bv = 3.4e38f; int bi = 0x7fffffff;
    for (int i=0;i<c;i++){
      if (listV[rr][i] <= fthr){
        const int idx = listI[rr][i];
        const float* wr = W + (size_t)idx*DD;
        float ss = 0.f;
        for (int k2=0;k2<256;k2++) ss = __fadd_rn(ss, __fmul_rn(zr[k2], wr[k2]));
        const float v = __fadd_rn(__fsub_rn(zs, __fmul_rn(2.0f, ss)), wsqS[idx]);
        minmerge(bv, bi, v, idx);
      }
    }
    riS[rr] = bi;
    const int grow = blk*BROWS + rr;
    rowcode[grow] = bi;
    out[O_IDX + grow] = (float)bi;
    atomicAdd(&cnt[bi], 1);
  }
  __syncthreads();

  /* ---- phase 4: epilogue (zq_st, dist) ---- */
  float distp = 0.f;
  const int GRp = tid >> 5;
  const int TX  = tid & 31;
  #pragma unroll
  for (int e=0; e<4; ++e){
    const int r    = GRp*4 + e;
    const int grow = blk*BROWS + r;
    const int gi   = riS[r];
    const float* wrow = W + (size_t)gi*DD;
    const float* zrow = zb + (size_t)r*DD;
    #pragma unroll
    for (int j=0;j<2;j++){
      const int d = 128*j + 4*TX;
      float4 w4 = *(const float4*)(wrow + d);
      float4 z4 = *(const float4*)(zrow + d);
      float4 o;
      o.x = z4.x + (w4.x - z4.x);
      o.y = z4.y + (w4.y - z4.y);
      o.z = z4.z + (w4.z - z4.z);
      o.w = z4.w + (w4.w - z4.w);
      *(float4*)&out[(size_t)grow*DD + d] = o;
      float dx;
      dx = w4.x - z4.x; distp += dx*dx;
      dx = w4.y - z4.y; distp += dx*dx;
      dx = w4.z - z4.z; distp += dx*dx;
      dx = w4.w - z4.w; distp += dx*dx;
    }
  }
  #pragma unroll
  for (int m=1; m<64; m<<=1) distp += __shfl_xor(distp, m);
  if ((tid & 63) == 0) atomicAdd(dist_acc, distp);
}

/* exclusive prefix sum over 1024 counts -> offs (with sentinel), pos */
__global__ __launch_bounds__(1024,1) void vq_prefix_kernel(
    const int* __restrict__ cnt, int* __restrict__ offs, int* __restrict__ pos)
{
  __shared__ int s[1024];
  const int tid = threadIdx.x;
  const int c = cnt[tid];
  s[tid] = c;
  __syncthreads();
  #pragma unroll
  for (int off=1; off<1024; off<<=1){
    int v = s[tid];
    int a = (tid >= off) ? s[tid-off] : 0;
    __syncthreads();
    s[tid] = v + a;
    __syncthreads();
  }
  const int ex = s[tid] - c;
  offs[tid] = ex;
  pos[tid]  = ex;
  if (tid == 1023) offs[1024] = NROWS;
}

/* bucket row ids by code */
__global__ __launch_bounds__(256,1) void vq_scatter_kernel(
    const int* __restrict__ rowcode, int* __restrict__ pos, int* __restrict__ bucket)
{
  const int r = blockIdx.x*256 + threadIdx.x;
  const int k = rowcode[r];
  const int slot = atomicAdd(&pos[k], 1);
  bucket[slot] = r;
}

/* balanced chunk-parallel segmented sum over the code-sorted bucket */
__global__ __launch_bounds__(256,4) void vq_chunksum_kernel(
    const float* __restrict__ ze, const int* __restrict__ bucket,
    const int* __restrict__ offs, float* __restrict__ st)
{
  __shared__ int offsS[1025];
  const int tid = threadIdx.x;
  for (int i=tid; i<1025; i+=256) offsS[i] = offs[i];
  __syncthreads();

  const int wv = tid >> 6, lane = tid & 63;
  const int j0 = (blockIdx.x*4 + wv)*32;

  int r, k;
  {
    const int j = j0 + (lane & 31);
    r = bucket[j];
    int lo = 0, hi = 1024;
    #pragma unroll
    for (int it=0; it<10; ++it){
      int mid = (lo + hi) >> 1;
      if (offsS[mid] <= j) lo = mid; else hi = mid;
    }
    k = lo;
  }

  float4 acc = {0.f,0.f,0.f,0.f};
  int kprev = __shfl(k, 0);
  #pragma unroll
  for (int g=0; g<4; ++g){
    float4 v[8]; int rk[8];
    #pragma unroll
    for (int i=0;i<8;i++){
      const int ri = __shfl(r, g*8+i);
      rk[i] = __shfl(k, g*8+i);
      v[i] = *(const float4*)&ze[(size_t)ri*DD + lane*4];
    }
    #pragma unroll
    for (int i=0;i<8;i++){
      if (rk[i] != kprev){
        atomicAdd(&st[(size_t)kprev*DD + lane*4 + 0], acc.x);
        atomicAdd(&st[(size_t)kprev*DD + lane*4 + 1], acc.y);
        atomicAdd(&st[(size_t)kprev*DD + lane*4 + 2], acc.z);
        atomicAdd(&st[(size_t)kprev*DD + lane*4 + 3], acc.w);
        acc = (float4){0.f,0.f,0.f,0.f};
        kprev = rk[i];
      }
      acc.x += v[i].x; acc.y += v[i].y; acc.z += v[i].z; acc.w += v[i].w;
    }
  }
  atomicAdd(&st[(size_t)kprev*DD + lane*4 + 0], acc.x);
  atomicAdd(&st[(size_t)kprev*DD + lane*4 + 1], acc.y);
  atomicAdd(&st[(size_t)kprev*DD + lane*4 + 2], acc.z);
  atomicAdd(&st[(size_t)kprev*DD + lane*4 + 3], acc.w);
}

/* EMA tail: mt_new, embedW_new, Nt_new, dist */
__global__ __launch_bounds__(256,1) void vq_tail_kernel(
    const float* __restrict__ mt, const float* __restrict__ Nt,
    const float* __restrict__ st, const int* __restrict__ cnt,
    const float* __restrict__ dist_acc, float* __restrict__ out)
{
  const float G   = 0.99f;
  const float OMG = (float)(1.0 - 0.99);
  const int i = blockIdx.x*256 + threadIdx.x;   /* 0..KD-1 */
  const int k = i >> 8;
  const float ntn = __fadd_rn(__fmul_rn(G, Nt[k]), __fmul_rn(OMG, (float)cnt[k]));
  const float mtn = __fadd_rn(__fmul_rn(G, mt[i]), __fmul_rn(OMG, st[i]));
  out[O_MT  + i] = mtn;
  out[O_EMB + i] = mtn / ntn;
  if ((i & 255) == 0) out[O_NT + k] = ntn;
  if (i == 0) out[O_DIST] = dist_acc[0] * (1.0f/16777216.0f);
}

extern "C" void kernel_launch(void* const* d_in, const int* in_sizes, int n_in,
                              void* d_out, int out_size, void* d_ws, size_t ws_size,
                              hipStream_t stream){
  const float* ze = (const float*)d_in[0];
  const float* W  = (const float*)d_in[1];
  const float* mt = (const float*)d_in[2];
  const float* Nt = (const float*)d_in[3];
  float* out  = (float*)d_out;
  float* ws   = (float*)d_ws;
  float*  wsq  = ws + WS_WSQ;
  bf16x8* wpk  = (bf16x8*)(ws + WS_WPK);
  int*    rowc = (int*)(ws + WS_ROWC);
  int*    buck = (int*)(ws + WS_BUCK);
  int*    offs = (int*)(ws + WS_OFFS);
  int*    pos  = (int*)(ws + WS_POS);
  int*    cnt  = (int*)(ws + WS_CNT);
  float*  dist = ws + WS_DIST;
  float*  st   = ws + WS_ST;

  /* zero cnt + dist(+pad) + st in one shot (contiguous) */
  hipMemsetAsync((void*)(ws + WS_CNT), 0, (size_t)(KC + 4 + KD)*sizeof(float), stream);
  vq_prep_kernel    <<<KC/4,        256, 0, stream>>>(W, wsq, wpk);
  vq_main_kernel    <<<NROWS/BROWS, 512, 0, stream>>>(ze, W, wpk, wsq, out, rowc, cnt, dist);
  vq_prefix_kernel  <<<1,          1024, 0, stream>>>(cnt, offs, pos);
  vq_scatter_kernel <<<NROWS/256,   256, 0, stream>>>(rowc, pos, buck);
  vq_chunksum_kernel<<<NROWS/128,   256, 0, stream>>>(ze, buck, offs, st);
  vq_tail_kernel    <<<KD/256,      256, 0, stream>>>(mt, Nt, st, cnt, dist, out);
}

// Round 15
// 357.414 us; speedup vs baseline: 1.6913x; 1.2309x over previous
//
#include <hip/hip_runtime.h>

#define NROWS 65536
#define KC    1024
#define DD    256
#define ND    (NROWS*DD)      /* 16777216 */
#define KD    (KC*DD)         /* 262144 */
#define BROWS 64              /* rows per screen block */
#define CAP   24              /* LDS candidate list capacity per row */
#define CEXP  12              /* exported (filtered) candidates per row */
#define MARGIN 3.0f           /* >=2E for bf16-screen vs exact-replica (~14 sigma) */

/* output offsets (floats), concatenated in reference return order */
#define O_ZQ   0
#define O_DIST ND
#define O_IDX  (ND+1)
#define O_EMB  (ND+1+NROWS)
#define O_MT   (O_EMB+KD)
#define O_NT   (O_MT+KD)

/* ws float offsets */
#define WS_WSQ   0
#define WS_WPK   KC                    /* 131072 floats = 512KB bf16 W frags */
#define WS_ROWC  (KC+131072)           /* NROWS ints */
#define WS_BUCK  (WS_ROWC+NROWS)       /* NROWS ints */
#define WS_OFFS  (WS_BUCK+NROWS)       /* 1028 ints (1025 used) */
#define WS_POS   (WS_OFFS+1028)        /* KC ints */
#define WS_CNT   (WS_POS+KC)           /* KC ints */
#define WS_DIST  (WS_CNT+KC)           /* 1 float + 3 pad */
#define WS_ST    (WS_DIST+4)           /* KD floats */
#define WS_CAND  (WS_ST+KD)            /* NROWS*CEXP u16 = NROWS*CEXP/2 floats */
#define WS_SEL   (WS_CAND+NROWS*CEXP/2)/* NROWS u16 */

typedef __attribute__((ext_vector_type(8))) short bf16x8;
typedef __attribute__((ext_vector_type(4))) float f32x4;

/* ===== exact-replica arithmetic contract (validated rounds 5-11,13,14) ==
   ref dist d2[r][c] = fadd( fsub( zsq[r], fmul(2, dot) ), wsq[c] )
   dot  = sequential ascending-k, SEPARATE mul+add roundings, single acc
   zsq/wsq = strict sequential sum of squares (mul+add, ascending)
   argmin  = first occurrence of min.
   Screen = bf16 MFMA (row-constant zsq dropped, absorbed in MARGIN);
   every code within MARGIN of the row's global screen min is rescored
   with the exact chain.  All chain bodies below are round-11 VERBATIM;
   this round only moves them between kernels (executor remap — the class
   round 14 proved correctness-safe). */

static __device__ __forceinline__ void minmerge(float& bv, int& bi, float ov, int oi){
  if (ov < bv || (ov == bv && oi < bi)) { bv = ov; bi = oi; }
}

static __device__ __forceinline__ unsigned short f2bf(float f){
  unsigned u = __float_as_uint(f);
  unsigned r = (u + 0x7FFFu + ((u>>16)&1u)) >> 16;   /* RNE */
  return (unsigned short)r;
}
static __device__ __forceinline__ bf16x8 cvt8(float4 a, float4 b){
  bf16x8 v;
  v[0]=(short)f2bf(a.x); v[1]=(short)f2bf(a.y); v[2]=(short)f2bf(a.z); v[3]=(short)f2bf(a.w);
  v[4]=(short)f2bf(b.x); v[5]=(short)f2bf(b.y); v[6]=(short)f2bf(b.z); v[7]=(short)f2bf(b.w);
  return v;
}

/* prologue: one wave per code. Lanes 0-31 pack bf16 B-fragments,
   lane 32 runs the exact wsq chain (scalar, round-11 verbatim). */
__global__ __launch_bounds__(256,1) void vq_prep_kernel(const float* __restrict__ W,
                                                        float* __restrict__ wsq,
                                                        bf16x8* __restrict__ wpk){
  const int wv = threadIdx.x>>6, lane = threadIdx.x&63;
  const int k = blockIdx.x*4 + wv;
  const float* wr = W + (size_t)k*DD;
  if (lane < 32){
    float4 x = *(const float4*)(wr + lane*8);
    float4 y = *(const float4*)(wr + lane*8 + 4);
    wpk[((k>>4)*8 + (lane>>2))*64 + (k&15) + 16*(lane&3)] = cvt8(x,y);
  } else if (lane == 32){
    float s = __fmul_rn(wr[0], wr[0]);
    for (int i=1;i<256;i++) s = __fadd_rn(s, __fmul_rn(wr[i], wr[i]));
    wsq[k] = s;
  }
}

/* screenA: 512 thr = 8 waves (2 row-groups x 4 col-groups), 64 rows x 1024
   codes per block, 1024 blocks. Screen + collect + filter + export.
   No chains, no epilogue. */
__global__ __launch_bounds__(512,2) void vq_screen_kernel(
    const float* __restrict__ ze, const bf16x8* __restrict__ wpk,
    const float* __restrict__ wsq,
    unsigned short* __restrict__ cand, unsigned short* __restrict__ selw)
{
  __shared__ bf16x8 apkS[2048];        /* 32 KB: A fragments, linear */
  __shared__ float  wsqS[KC];          /* 4 KB */
  __shared__ float  gminW[8][BROWS];   /* 2 KB */
  __shared__ int    cntS[BROWS];
  __shared__ float  listV[BROWS][CAP]; /* 6 KB */
  __shared__ int    listI[BROWS][CAP]; /* 6 KB */

  const int tid = threadIdx.x;
  const int blk = blockIdx.x;
  const float* zb = ze + (size_t)blk*BROWS*DD;

  /* ---- phase 1: convert z tile to A fragments + init ---- */
  #pragma unroll
  for (int it=0; it<4; ++it){
    const int g  = it*512 + tid;
    const int r  = g >> 5;
    const int kb = g & 31;
    float4 a = *(const float4*)&zb[(size_t)r*DD + kb*8];
    float4 b = *(const float4*)&zb[(size_t)r*DD + kb*8 + 4];
    apkS[((r>>4)*8 + (kb>>2))*64 + (r&15) + 16*(kb&3)] = cvt8(a,b);
  }
  wsqS[tid]     = wsq[tid];
  wsqS[tid+512] = wsq[tid+512];
  if (tid < BROWS) cntS[tid] = 0;
  __syncthreads();

  /* ---- phase 2: MFMA screen + per-group min + candidate collection ---- */
  const int lane = tid & 63;
  const int wv   = tid >> 6;
  const int rg   = wv >> 2;
  const int cg   = wv & 3;

  #pragma unroll
  for (int p=0; p<2; ++p){
    f32x4 acc[2][8];
    #pragma unroll
    for (int mt=0; mt<2; ++mt)
      #pragma unroll
      for (int nt=0; nt<8; ++nt)
        acc[mt][nt] = (f32x4){0.f,0.f,0.f,0.f};

    #pragma unroll
    for (int s=0; s<8; ++s){
      bf16x8 af[2], bf[8];
      #pragma unroll
      for (int mt=0; mt<2; ++mt)
        af[mt] = apkS[((rg*2+mt)*8 + s)*64 + lane];
      #pragma unroll
      for (int nt=0; nt<8; ++nt)
        bf[nt] = wpk[(size_t)(((cg*16 + p*8 + nt)*8 + s)*64 + lane)];
      #pragma unroll
      for (int mt=0; mt<2; ++mt)
        #pragma unroll
        for (int nt=0; nt<8; ++nt)
          acc[mt][nt] = __builtin_amdgcn_mfma_f32_16x16x32_bf16(af[mt], bf[nt], acc[mt][nt], 0,0,0);
    }

    /* screen value = wsq - 2*dot (row-constant zsq dropped) */
    #pragma unroll
    for (int mt=0; mt<2; ++mt){
      #pragma unroll
      for (int r=0; r<4; ++r){
        const int row = rg*32 + mt*16 + (lane>>4)*4 + r;
        float dv[8]; float mn = 3.4e38f;
        #pragma unroll
        for (int nt=0; nt<8; ++nt){
          const int col = (cg*16 + p*8 + nt)*16 + (lane&15);
          dv[nt] = __fsub_rn(wsqS[col], __fmul_rn(2.0f, acc[mt][nt][r]));
          mn = fminf(mn, dv[nt]);
        }
        #pragma unroll
        for (int m=1; m<16; m<<=1) mn = fminf(mn, __shfl_xor(mn, m));
        if ((lane & 15) == 0) gminW[p*4+cg][row] = mn;
        const float thr = mn + MARGIN;
        #pragma unroll
        for (int nt=0; nt<8; ++nt){
          if (dv[nt] <= thr){
            int slot = atomicAdd(&cntS[row], 1);
            if (slot < CAP){
              listV[row][slot] = dv[nt];
              listI[row][slot] = (cg*16 + p*8 + nt)*16 + (lane&15);
            }
          }
        }
      }
    }
  }
  __syncthreads();

  /* ---- phase 3': global-min filter + export (round-11 filter verbatim) ---- */
  if (tid < BROWS){
    const int rr = tid;
    float g = gminW[0][rr];
    #pragma unroll
    for (int q=1;q<8;q++) g = fminf(g, gminW[q][rr]);
    const float fthr = g + MARGIN;
    int c = cntS[rr]; if (c > CAP) c = CAP;
    const int grow = blk*BROWS + rr;
    int sel = 0;
    for (int i=0;i<c;i++){
      if (listV[rr][i] <= fthr && sel < CEXP){
        cand[(size_t)grow*CEXP + sel] = (unsigned short)listI[rr][i];
        sel++;
      }
    }
    selw[grow] = (unsigned short)sel;
  }
}

/* decideB: 1 thread per row, whole chip. Round-11 chain bodies verbatim. */
__global__ __launch_bounds__(256,1) void vq_decide_kernel(
    const float* __restrict__ ze, const float* __restrict__ W,
    const float* __restrict__ wsq,
    const unsigned short* __restrict__ cand, const unsigned short* __restrict__ selw,
    int* __restrict__ rowcode, int* __restrict__ cnt, float* __restrict__ out)
{
  const int row = blockIdx.x*256 + threadIdx.x;
  const float* zr = ze + (size_t)row*DD;
  /* exact zsq chain */
  float zs = __fmul_rn(zr[0], zr[0]);
  for (int i=1;i<256;i++) zs = __fadd_rn(zs, __fmul_rn(zr[i], zr[i]));
  const int sel = selw[row];
  float bv = 3.4e38f; int bi = 0x7fffffff;
  for (int i=0;i<sel;i++){
    const int idx = cand[(size_t)row*CEXP + i];
    const float* wr = W + (size_t)idx*DD;
    float ss = 0.f;
    for (int k2=0;k2<256;k2++) ss = __fadd_rn(ss, __fmul_rn(zr[k2], wr[k2]));
    const float v = __fadd_rn(__fsub_rn(zs, __fmul_rn(2.0f, ss)), wsq[idx]);
    minmerge(bv, bi, v, idx);
  }
  rowcode[row] = bi;
  out[O_IDX + row] = (float)bi;
  atomicAdd(&cnt[bi], 1);
}

/* zqC: fully-coalesced zq_st + dist. 64 consecutive lanes share one row. */
__global__ __launch_bounds__(256,1) void vq_zq_kernel(
    const float* __restrict__ ze, const float* __restrict__ W,
    const int* __restrict__ rowcode, float* __restrict__ out,
    float* __restrict__ dist_acc)
{
  const int t = blockIdx.x*256 + threadIdx.x;    /* 0..524287 */
  float distp = 0.f;
  #pragma unroll
  for (int it=0; it<8; ++it){
    const int fi  = it*524288 + t;               /* float4 index < 4194304 */
    const int row = fi >> 6;
    const int d   = (fi & 63) * 4;
    const int gi  = rowcode[row];
    float4 w4 = *(const float4*)&W[(size_t)gi*DD + d];
    float4 z4 = *(const float4*)&ze[(size_t)fi*4];
    float4 o;
    o.x = z4.x + (w4.x - z4.x);
    o.y = z4.y + (w4.y - z4.y);
    o.z = z4.z + (w4.z - z4.z);
    o.w = z4.w + (w4.w - z4.w);
    *(float4*)&out[(size_t)fi*4] = o;
    float dx;
    dx = w4.x - z4.x; distp += dx*dx;
    dx = w4.y - z4.y; distp += dx*dx;
    dx = w4.z - z4.z; distp += dx*dx;
    dx = w4.w - z4.w; distp += dx*dx;
  }
  #pragma unroll
  for (int m=1; m<64; m<<=1) distp += __shfl_xor(distp, m);
  if ((threadIdx.x & 63) == 0) atomicAdd(dist_acc, distp);
}

/* exclusive prefix sum over 1024 counts -> offs (with sentinel), pos */
__global__ __launch_bounds__(1024,1) void vq_prefix_kernel(
    const int* __restrict__ cnt, int* __restrict__ offs, int* __restrict__ pos)
{
  __shared__ int s[1024];
  const int tid = threadIdx.x;
  const int c = cnt[tid];
  s[tid] = c;
  __syncthreads();
  #pragma unroll
  for (int off=1; off<1024; off<<=1){
    int v = s[tid];
    int a = (tid >= off) ? s[tid-off] : 0;
    __syncthreads();
    s[tid] = v + a;
    __syncthreads();
  }
  const int ex = s[tid] - c;
  offs[tid] = ex;
  pos[tid]  = ex;
  if (tid == 1023) offs[1024] = NROWS;
}

/* bucket row ids by code */
__global__ __launch_bounds__(256,1) void vq_scatter_kernel(
    const int* __restrict__ rowcode, int* __restrict__ pos, int* __restrict__ bucket)
{
  const int r = blockIdx.x*256 + threadIdx.x;
  const int k = rowcode[r];
  const int slot = atomicAdd(&pos[k], 1);
  bucket[slot] = r;
}

/* balanced chunk-parallel segmented sum over the code-sorted bucket */
__global__ __launch_bounds__(256,4) void vq_chunksum_kernel(
    const float* __restrict__ ze, const int* __restrict__ bucket,
    const int* __restrict__ offs, float* __restrict__ st)
{
  __shared__ int offsS[1025];
  const int tid = threadIdx.x;
  for (int i=tid; i<1025; i+=256) offsS[i] = offs[i];
  __syncthreads();

  const int wv = tid >> 6, lane = tid & 63;
  const int j0 = (blockIdx.x*4 + wv)*32;

  int r, k;
  {
    const int j = j0 + (lane & 31);
    r = bucket[j];
    int lo = 0, hi = 1024;
    #pragma unroll
    for (int it=0; it<10; ++it){
      int mid = (lo + hi) >> 1;
      if (offsS[mid] <= j) lo = mid; else hi = mid;
    }
    k = lo;
  }

  float4 acc = {0.f,0.f,0.f,0.f};
  int kprev = __shfl(k, 0);
  #pragma unroll
  for (int g=0; g<4; ++g){
    float4 v[8]; int rk[8];
    #pragma unroll
    for (int i=0;i<8;i++){
      const int ri = __shfl(r, g*8+i);
      rk[i] = __shfl(k, g*8+i);
      v[i] = *(const float4*)&ze[(size_t)ri*DD + lane*4];
    }
    #pragma unroll
    for (int i=0;i<8;i++){
      if (rk[i] != kprev){
        atomicAdd(&st[(size_t)kprev*DD + lane*4 + 0], acc.x);
        atomicAdd(&st[(size_t)kprev*DD + lane*4 + 1], acc.y);
        atomicAdd(&st[(size_t)kprev*DD + lane*4 + 2], acc.z);
        atomicAdd(&st[(size_t)kprev*DD + lane*4 + 3], acc.w);
        acc = (float4){0.f,0.f,0.f,0.f};
        kprev = rk[i];
      }
      acc.x += v[i].x; acc.y += v[i].y; acc.z += v[i].z; acc.w += v[i].w;
    }
  }
  atomicAdd(&st[(size_t)kprev*DD + lane*4 + 0], acc.x);
  atomicAdd(&st[(size_t)kprev*DD + lane*4 + 1], acc.y);
  atomicAdd(&st[(size_t)kprev*DD + lane*4 + 2], acc.z);
  atomicAdd(&st[(size_t)kprev*DD + lane*4 + 3], acc.w);
}

/* EMA tail: mt_new, embedW_new, Nt_new, dist */
__global__ __launch_bounds__(256,1) void vq_tail_kernel(
    const float* __restrict__ mt, const float* __restrict__ Nt,
    const float* __restrict__ st, const int* __restrict__ cnt,
    const float* __restrict__ dist_acc, float* __restrict__ out)
{
  const float G   = 0.99f;
  const float OMG = (float)(1.0 - 0.99);
  const int i = blockIdx.x*256 + threadIdx.x;   /* 0..KD-1 */
  const int k = i >> 8;
  const float ntn = __fadd_rn(__fmul_rn(G, Nt[k]), __fmul_rn(OMG, (float)cnt[k]));
  const float mtn = __fadd_rn(__fmul_rn(G, mt[i]), __fmul_rn(OMG, st[i]));
  out[O_MT  + i] = mtn;
  out[O_EMB + i] = mtn / ntn;
  if ((i & 255) == 0) out[O_NT + k] = ntn;
  if (i == 0) out[O_DIST] = dist_acc[0] * (1.0f/16777216.0f);
}

extern "C" void kernel_launch(void* const* d_in, const int* in_sizes, int n_in,
                              void* d_out, int out_size, void* d_ws, size_t ws_size,
                              hipStream_t stream){
  const float* ze = (const float*)d_in[0];
  const float* W  = (const float*)d_in[1];
  const float* mt = (const float*)d_in[2];
  const float* Nt = (const float*)d_in[3];
  float* out  = (float*)d_out;
  float* ws   = (float*)d_ws;
  float*  wsq  = ws + WS_WSQ;
  bf16x8* wpk  = (bf16x8*)(ws + WS_WPK);
  int*    rowc = (int*)(ws + WS_ROWC);
  int*    buck = (int*)(ws + WS_BUCK);
  int*    offs = (int*)(ws + WS_OFFS);
  int*    pos  = (int*)(ws + WS_POS);
  int*    cnt  = (int*)(ws + WS_CNT);
  float*  dist = ws + WS_DIST;
  float*  st   = ws + WS_ST;
  unsigned short* cand = (unsigned short*)(ws + WS_CAND);
  unsigned short* selw = (unsigned short*)(ws + WS_SEL);

  /* zero cnt + dist(+pad) + st in one shot (contiguous) */
  hipMemsetAsync((void*)(ws + WS_CNT), 0, (size_t)(KC + 4 + KD)*sizeof(float), stream);
  vq_prep_kernel    <<<KC/4,        256, 0, stream>>>(W, wsq, wpk);
  vq_screen_kernel  <<<NROWS/BROWS, 512, 0, stream>>>(ze, wpk, wsq, cand, selw);
  vq_decide_kernel  <<<NROWS/256,   256, 0, stream>>>(ze, W, wsq, cand, selw, rowc, cnt, out);
  vq_zq_kernel      <<<2048,        256, 0, stream>>>(ze, W, rowc, out, dist);
  vq_prefix_kernel  <<<1,          1024, 0, stream>>>(cnt, offs, pos);
  vq_scatter_kernel <<<NROWS/256,   256, 0, stream>>>(rowc, pos, buck);
  vq_chunksum_kernel<<<NROWS/128,   256, 0, stream>>>(ze, buck, offs, st);
  vq_tail_kernel    <<<KD/256,      256, 0, stream>>>(mt, Nt, st, cnt, dist, out);
}